// Round 1
// baseline (355.776 us; speedup 1.0000x reference)
//
#include <hip/hip_runtime.h>
#include <hip/hip_bf16.h>
#include <cstdint>
#include <cstddef>

// ---------------------------------------------------------------------------
// Attention block on MI355X (gfx950), bf16 MFMA everywhere.
//   x = LN(seq); q,k,v = x@W{q,k,v}.T + b; s = q.k/8
//   w = sigmoid(s-mu)*exp(s) = e^2/(e+e^mu), e=exp(s);  P = w / rowsum(w)
//   out = (P @ v, heads merged) @ Wo.T + bo
// ---------------------------------------------------------------------------

typedef __bf16 bf16_t;
typedef __bf16 bf16x4 __attribute__((ext_vector_type(4)));
typedef __bf16 bf16x8 __attribute__((ext_vector_type(8)));
typedef float  f32x4  __attribute__((ext_vector_type(4)));

#define MFMA16(a, b, c) __builtin_amdgcn_mfma_f32_16x16x32_bf16((a), (b), (c), 0, 0, 0)

// async global->LDS, 16B per lane. LDS dest must be wave-uniform base + lane*16.
__device__ __forceinline__ void gload16(void* lds, const void* g) {
  __builtin_amdgcn_global_load_lds(
      (__attribute__((address_space(1))) void*)(uintptr_t)g,
      (__attribute__((address_space(3))) void*)(uint32_t)(uintptr_t)lds,
      16, 0, 0);
}

// ---------------- weights fp32 -> bf16 (4 x 1M elements, packed) -----------
__global__ __launch_bounds__(256) void cvt_w_k(
    const float* __restrict__ s0, const float* __restrict__ s1,
    const float* __restrict__ s2, const float* __restrict__ s3,
    bf16_t* __restrict__ dst)
{
  const float* src = blockIdx.y == 0 ? s0 : blockIdx.y == 1 ? s1
                   : blockIdx.y == 2 ? s2 : s3;
  int i = blockIdx.x * 256 + threadIdx.x;          // float4 index
  float4 v = ((const float4*)src)[i];
  bf16x4 o = { (bf16_t)v.x, (bf16_t)v.y, (bf16_t)v.z, (bf16_t)v.w };
  *(bf16x4*)(dst + (((size_t)blockIdx.y) << 20) + (size_t)i * 4) = o;
}

// ---------------- LayerNorm (row = 1024 fp32) -> bf16 ----------------------
__global__ __launch_bounds__(256) void ln_k(
    const float* __restrict__ x, const float* __restrict__ gamma,
    const float* __restrict__ beta, bf16_t* __restrict__ out)
{
  int row = blockIdx.x;                  // 8192 rows
  int tid = threadIdx.x;                 // 256 threads, one float4 each
  float4 v = ((const float4*)(x + (size_t)row * 1024))[tid];
  float s  = v.x + v.y + v.z + v.w;
  float ss = v.x * v.x + v.y * v.y + v.z * v.z + v.w * v.w;
#pragma unroll
  for (int m = 1; m < 64; m <<= 1) { s += __shfl_xor(s, m); ss += __shfl_xor(ss, m); }
  __shared__ float sh_s[4], sh_q[4];
  int w = tid >> 6;
  if ((tid & 63) == 0) { sh_s[w] = s; sh_q[w] = ss; }
  __syncthreads();
  s  = sh_s[0] + sh_s[1] + sh_s[2] + sh_s[3];
  ss = sh_q[0] + sh_q[1] + sh_q[2] + sh_q[3];
  float mean = s * (1.0f / 1024.0f);
  float var  = ss * (1.0f / 1024.0f) - mean * mean;
  float rstd = rsqrtf(var + 1e-6f);
  float4 gv = ((const float4*)gamma)[tid];
  float4 bv = ((const float4*)beta)[tid];
  bf16x4 o = { (bf16_t)((v.x - mean) * rstd * gv.x + bv.x),
               (bf16_t)((v.y - mean) * rstd * gv.y + bv.y),
               (bf16_t)((v.z - mean) * rstd * gv.z + bv.z),
               (bf16_t)((v.w - mean) * rstd * gv.w + bv.w) };
  *(bf16x4*)(out + (size_t)row * 1024 + tid * 4) = o;
}

// ---------------- NT GEMM: C[M,N] = A[M,K] * Bw[N,K]^T + bias --------------
// 128x128 tile, BK=32, 256 thr = 4 waves (2x2), wave = 64x64 = 4x4 MFMA frags.
// mode 0: bf16 out, [B,H,S,64] split-head scatter (q,k)
// mode 1: bf16 out, [B,H,64,S] transposed scatter (v)
// mode 2: fp32 out, row-major [M,N]
__global__ __launch_bounds__(256) void gemm_bt(
    const bf16_t* __restrict__ A, const bf16_t* __restrict__ Bw,
    const float* __restrict__ bias, void* __restrict__ Cout,
    int M, int N, int K, int mode)
{
  __shared__ __align__(16) bf16_t a_lds[128][32];
  __shared__ __align__(16) bf16_t b_lds[128][32];
  const int tid = threadIdx.x;
  const int l = tid & 63, w = tid >> 6;
  const int wr = w >> 1, wc = w & 1;
  const int m0 = blockIdx.y * 128, n0 = blockIdx.x * 128;
  const int lr = l & 15, lg = l >> 4;

  f32x4 acc[4][4] = {};

  const int srow = tid >> 2;             // 0..63, staged row
  const int scol = (tid & 3) * 8;        // element offset in K-chunk
  const bf16_t* ag = A  + (size_t)(m0 + srow) * K + scol;
  const bf16_t* bg = Bw + (size_t)(n0 + srow) * K + scol;
  char* a_l0 = (char*)a_lds + tid * 16;
  char* b_l0 = (char*)b_lds + tid * 16;

  for (int k0 = 0; k0 < K; k0 += 32) {
    gload16(a_l0,        ag + k0);
    gload16(a_l0 + 4096, ag + (size_t)64 * K + k0);
    gload16(b_l0,        bg + k0);
    gload16(b_l0 + 4096, bg + (size_t)64 * K + k0);
    __syncthreads();                     // drains vmcnt before barrier
    bf16x8 af[4], bf[4];
#pragma unroll
    for (int i = 0; i < 4; ++i) {
      af[i] = *(const bf16x8*)&a_lds[wr * 64 + i * 16 + lr][lg * 8];
      bf[i] = *(const bf16x8*)&b_lds[wc * 64 + i * 16 + lr][lg * 8];
    }
#pragma unroll
    for (int i = 0; i < 4; ++i)
#pragma unroll
      for (int j = 0; j < 4; ++j)
        acc[i][j] = MFMA16(af[i], bf[j], acc[i][j]);
    __syncthreads();
  }

  float bs[4];
#pragma unroll
  for (int j = 0; j < 4; ++j) bs[j] = bias[n0 + wc * 64 + j * 16 + lr];

#pragma unroll
  for (int i = 0; i < 4; ++i) {
#pragma unroll
    for (int j = 0; j < 4; ++j) {
#pragma unroll
      for (int r = 0; r < 4; ++r) {
        int row = m0 + wr * 64 + i * 16 + lg * 4 + r;   // C/D: row=(l>>4)*4+r
        int col = n0 + wc * 64 + j * 16 + lr;           //      col=l&15
        float v = acc[i][j][r] + bs[j];
        if (mode == 2) {
          ((float*)Cout)[(size_t)row * N + col] = v;
        } else {
          int bb = row >> 11, s = row & 2047, h = col >> 6, d = col & 63;
          size_t idx;
          if (mode == 0) idx = ((((size_t)bb * 16 + h) * 2048 + s) << 6) + d;
          else           idx = (((size_t)bb * 16 + h) * 64 + d) * 2048 + s;
          ((bf16_t*)Cout)[idx] = (bf16_t)v;
        }
      }
    }
  }
}

// ---------------- fused attention ------------------------------------------
// grid (S/64, H, B), 256 thr = 4 waves; wave owns 16 q-rows.
// q,k: [B*H][S][64] bf16; vT: [B*H][64][S] bf16; out: [B][S][1024] bf16.
__global__ __launch_bounds__(256) void attn_k(
    const bf16_t* __restrict__ q, const bf16_t* __restrict__ k,
    const bf16_t* __restrict__ vT, const float* __restrict__ mu_p,
    bf16_t* __restrict__ out)
{
  const int S = 2048;
  const int qt = blockIdx.x, h = blockIdx.y, b = blockIdx.z;
  const int bh = b * 16 + h;
  const bf16_t* qb = q  + ((size_t)bh * S + qt * 64) * 64;
  const bf16_t* kb = k  + (size_t)bh * S * 64;
  const bf16_t* vb = vT + (size_t)bh * 64 * S;
  const float emu = __expf(mu_p[0]);

  __shared__ __align__(16) bf16_t q_lds[64][64];
  __shared__ __align__(16) bf16_t k_lds[64][64];
  __shared__ __align__(16) bf16_t v_lds[64][64];      // [d][kseq-local]
  __shared__ __align__(16) bf16_t p_lds[4][16][64];   // per-wave P tile

  const int tid = threadIdx.x, l = tid & 63, w = tid >> 6;
  const int lr = l & 15, lg = l >> 4;

  gload16((char*)q_lds + tid * 16,        (const char*)qb + tid * 16);
  gload16((char*)q_lds + 4096 + tid * 16, (const char*)qb + 4096 + tid * 16);
  __syncthreads();

  bf16x8 qa[2];
  qa[0] = *(const bf16x8*)&q_lds[w * 16 + lr][lg * 8];
  qa[1] = *(const bf16x8*)&q_lds[w * 16 + lr][32 + lg * 8];

  f32x4 o[4] = {};                 // 4 d-tiles of 16, rows (lg*4+r)
  float rsum[4] = {0.f, 0.f, 0.f, 0.f};

  for (int t = 0; t < 32; ++t) {
    const char* ksrc = (const char*)(kb + (size_t)t * 64 * 64);
    gload16((char*)k_lds + tid * 16,        ksrc + tid * 16);
    gload16((char*)k_lds + 4096 + tid * 16, ksrc + 4096 + tid * 16);
    {
      int r = tid >> 3, cb = (tid & 7) * 16;
      const char* vsrc = (const char*)vb + (size_t)t * 128;  // t*64 elems
      gload16((char*)v_lds + tid * 16,        vsrc + (size_t)r * 4096 + cb);
      gload16((char*)v_lds + 4096 + tid * 16, vsrc + (size_t)(r + 32) * 4096 + cb);
    }
    __syncthreads();

    // scores: S[16 x 64] per wave, K=64 over head dim
    f32x4 sfr[4];
#pragma unroll
    for (int cc = 0; cc < 4; ++cc) {
      f32x4 a = {};
      bf16x8 kf0 = *(const bf16x8*)&k_lds[cc * 16 + lr][lg * 8];
      bf16x8 kf1 = *(const bf16x8*)&k_lds[cc * 16 + lr][32 + lg * 8];
      a = MFMA16(qa[0], kf0, a);
      a = MFMA16(qa[1], kf1, a);
      sfr[cc] = a;
    }
    // w = e^2/(e+emu), e = exp(s/8); accumulate rowsums; P -> LDS (bf16)
#pragma unroll
    for (int cc = 0; cc < 4; ++cc) {
#pragma unroll
      for (int r = 0; r < 4; ++r) {
        float sv = sfr[cc][r] * 0.125f;
        float e = __expf(sv);
        float wgt = e * e * __builtin_amdgcn_rcpf(e + emu);
        rsum[r] += wgt;
        p_lds[w][lg * 4 + r][cc * 16 + lr] = (bf16_t)wgt;
      }
    }
    // PV: O[16 x 64] += P[16 x 64] * V[64 x 64]
#pragma unroll
    for (int cc = 0; cc < 4; ++cc) {
      bf16x8 pa0 = *(const bf16x8*)&p_lds[w][lr][lg * 8];
      bf16x8 vf0 = *(const bf16x8*)&v_lds[cc * 16 + lr][lg * 8];
      o[cc] = MFMA16(pa0, vf0, o[cc]);
      bf16x8 pa1 = *(const bf16x8*)&p_lds[w][lr][32 + lg * 8];
      bf16x8 vf1 = *(const bf16x8*)&v_lds[cc * 16 + lr][32 + lg * 8];
      o[cc] = MFMA16(pa1, vf1, o[cc]);
    }
    __syncthreads();
  }

  // normalize by row sums (16-lane reduce stays inside the row group)
#pragma unroll
  for (int r = 0; r < 4; ++r) {
    rsum[r] += __shfl_xor(rsum[r], 1);
    rsum[r] += __shfl_xor(rsum[r], 2);
    rsum[r] += __shfl_xor(rsum[r], 4);
    rsum[r] += __shfl_xor(rsum[r], 8);
    rsum[r] = 1.0f / rsum[r];
  }
#pragma unroll
  for (int cc = 0; cc < 4; ++cc)
#pragma unroll
    for (int r = 0; r < 4; ++r) {
      int srow = qt * 64 + w * 16 + lg * 4 + r;
      int col  = h * 64 + cc * 16 + lr;
      out[((size_t)b * 2048 + srow) * 1024 + col] = (bf16_t)(o[cc][r] * rsum[r]);
    }
}

// ---------------------------------------------------------------------------
extern "C" void kernel_launch(void* const* d_in, const int* in_sizes, int n_in,
                              void* d_out, int out_size, void* d_ws, size_t ws_size,
                              hipStream_t stream) {
  const float* seq = (const float*)d_in[0];
  const float* g   = (const float*)d_in[1];
  const float* be  = (const float*)d_in[2];
  const float* Wq  = (const float*)d_in[3];
  const float* bq  = (const float*)d_in[4];
  const float* Wk  = (const float*)d_in[5];
  const float* bk  = (const float*)d_in[6];
  const float* Wv  = (const float*)d_in[7];
  const float* bv  = (const float*)d_in[8];
  const float* Wo  = (const float*)d_in[9];
  const float* bo  = (const float*)d_in[10];
  const float* mu  = (const float*)d_in[11];

  char* ws = (char*)d_ws;
  bf16_t* xb   = (bf16_t*)ws;  ws += (size_t)8192 * 1024 * 2;   // 16 MB
  bf16_t* wAll = (bf16_t*)ws;  ws += (size_t)4 * 1024 * 1024 * 2; // 8 MB
  bf16_t* qb   = (bf16_t*)ws;  ws += (size_t)8192 * 1024 * 2;
  bf16_t* kbuf = (bf16_t*)ws;  ws += (size_t)8192 * 1024 * 2;
  bf16_t* vtb  = (bf16_t*)ws;  ws += (size_t)8192 * 1024 * 2;
  bf16_t* ab   = (bf16_t*)ws;  ws += (size_t)8192 * 1024 * 2;
  bf16_t* wqb = wAll;
  bf16_t* wkb = wAll + (size_t)1 * 1024 * 1024;
  bf16_t* wvb = wAll + (size_t)2 * 1024 * 1024;
  bf16_t* wob = wAll + (size_t)3 * 1024 * 1024;

  dim3 blk(256);
  cvt_w_k<<<dim3(1024, 4), blk, 0, stream>>>(Wq, Wk, Wv, Wo, wAll);
  ln_k<<<dim3(8192), blk, 0, stream>>>(seq, g, be, xb);
  gemm_bt<<<dim3(8, 64), blk, 0, stream>>>(xb, wqb, bq, qb,   8192, 1024, 1024, 0);
  gemm_bt<<<dim3(8, 64), blk, 0, stream>>>(xb, wkb, bk, kbuf, 8192, 1024, 1024, 0);
  gemm_bt<<<dim3(8, 64), blk, 0, stream>>>(xb, wvb, bv, vtb,  8192, 1024, 1024, 1);
  attn_k<<<dim3(32, 16, 4), blk, 0, stream>>>(qb, kbuf, vtb, mu, ab);
  gemm_bt<<<dim3(8, 64), blk, 0, stream>>>(ab, wob, bo, d_out, 8192, 1024, 1024, 2);
}

// Round 2
// 332.898 us; speedup vs baseline: 1.0687x; 1.0687x over previous
//
#include <hip/hip_runtime.h>
#include <hip/hip_bf16.h>
#include <cstdint>
#include <cstddef>

// ---------------------------------------------------------------------------
// Attention block on MI355X (gfx950), bf16 MFMA everywhere.
//   x = LN(seq); q,k,v = x@W{q,k,v}.T + b (q pre-scaled by 1/8, exact in bf16)
//   s = q.k ; w = sigmoid(s-mu)*exp(s) = e^2/(e+e^mu), e=exp(s)
//   P = w / rowsum(w); out = (P @ v, heads merged) @ Wo.T + bo
// ---------------------------------------------------------------------------

typedef __bf16 bf16_t;
typedef __bf16 bf16x4 __attribute__((ext_vector_type(4)));
typedef __bf16 bf16x8 __attribute__((ext_vector_type(8)));
typedef float  f32x4  __attribute__((ext_vector_type(4)));

#define MFMA16(a, b, c) __builtin_amdgcn_mfma_f32_16x16x32_bf16((a), (b), (c), 0, 0, 0)

__device__ __forceinline__ void gload16(void* lds, const void* g) {
  __builtin_amdgcn_global_load_lds(
      (__attribute__((address_space(1))) void*)(uintptr_t)g,
      (__attribute__((address_space(3))) void*)(uint32_t)(uintptr_t)lds,
      16, 0, 0);
}

// ---------------- weights fp32 -> bf16 (4 x 1M elements, packed) -----------
__global__ __launch_bounds__(256) void cvt_w_k(
    const float* __restrict__ s0, const float* __restrict__ s1,
    const float* __restrict__ s2, const float* __restrict__ s3,
    bf16_t* __restrict__ dst)
{
  const float* src = blockIdx.y == 0 ? s0 : blockIdx.y == 1 ? s1
                   : blockIdx.y == 2 ? s2 : s3;
  int i = blockIdx.x * 256 + threadIdx.x;
  float4 v = ((const float4*)src)[i];
  bf16x4 o = { (bf16_t)v.x, (bf16_t)v.y, (bf16_t)v.z, (bf16_t)v.w };
  *(bf16x4*)(dst + (((size_t)blockIdx.y) << 20) + (size_t)i * 4) = o;
}

// ---------------- LayerNorm (row = 1024 fp32) -> bf16 ----------------------
__global__ __launch_bounds__(256) void ln_k(
    const float* __restrict__ x, const float* __restrict__ gamma,
    const float* __restrict__ beta, bf16_t* __restrict__ out)
{
  int row = blockIdx.x;
  int tid = threadIdx.x;
  float4 v = ((const float4*)(x + (size_t)row * 1024))[tid];
  float s  = v.x + v.y + v.z + v.w;
  float ss = v.x * v.x + v.y * v.y + v.z * v.z + v.w * v.w;
#pragma unroll
  for (int m = 1; m < 64; m <<= 1) { s += __shfl_xor(s, m); ss += __shfl_xor(ss, m); }
  __shared__ float sh_s[4], sh_q[4];
  int w = tid >> 6;
  if ((tid & 63) == 0) { sh_s[w] = s; sh_q[w] = ss; }
  __syncthreads();
  s  = sh_s[0] + sh_s[1] + sh_s[2] + sh_s[3];
  ss = sh_q[0] + sh_q[1] + sh_q[2] + sh_q[3];
  float mean = s * (1.0f / 1024.0f);
  float var  = ss * (1.0f / 1024.0f) - mean * mean;
  float rstd = rsqrtf(var + 1e-6f);
  float4 gv = ((const float4*)gamma)[tid];
  float4 bv = ((const float4*)beta)[tid];
  bf16x4 o = { (bf16_t)((v.x - mean) * rstd * gv.x + bv.x),
               (bf16_t)((v.y - mean) * rstd * gv.y + bv.y),
               (bf16_t)((v.z - mean) * rstd * gv.z + bv.z),
               (bf16_t)((v.w - mean) * rstd * gv.w + bv.w) };
  *(bf16x4*)(out + (size_t)row * 1024 + tid * 4) = o;
}

// ---------------- NT GEMM: C[M,N] = A[M,K] * Bw[N,K]^T + bias --------------
// 128x128 tile, BK=32, 2-phase double-buffered staging (one barrier/K-step).
// fused=1: N=3072 packed qkv -> scatter (q: [B,H,S,64] scaled 1/8, k same,
//          v transposed [B,H,64,S]); fused=0: fp32 row-major out (o-proj).
__global__ __launch_bounds__(256) void gemm_bt(
    const bf16_t* __restrict__ A, const bf16_t* __restrict__ Bw,
    const float* __restrict__ b0, const float* __restrict__ b1,
    const float* __restrict__ b2,
    void* __restrict__ o0, void* __restrict__ o1, void* __restrict__ o2,
    int M, int N, int K, int fused)
{
  __shared__ __align__(16) bf16_t a_lds[2][128][32];
  __shared__ __align__(16) bf16_t b_lds[2][128][32];
  const int tid = threadIdx.x;
  const int l = tid & 63, w = tid >> 6;
  const int wr = w >> 1, wc = w & 1;
  const int m0 = blockIdx.y * 128, n0 = blockIdx.x * 128;
  const int lr = l & 15, lg = l >> 4;

  f32x4 acc[4][4] = {};

  const int srow = tid >> 2;
  const int scol = (tid & 3) * 8;
  const bf16_t* ag = A  + (size_t)(m0 + srow) * K + scol;
  const bf16_t* bg = Bw + (size_t)(n0 + srow) * K + scol;

  // prologue stage
  gload16((char*)a_lds[0] + tid * 16,        ag);
  gload16((char*)a_lds[0] + 4096 + tid * 16, ag + (size_t)64 * K);
  gload16((char*)b_lds[0] + tid * 16,        bg);
  gload16((char*)b_lds[0] + 4096 + tid * 16, bg + (size_t)64 * K);
  __syncthreads();

  int cur = 0;
  for (int k0 = 0; k0 < K; k0 += 32) {
    if (k0 + 32 < K) {
      gload16((char*)a_lds[cur ^ 1] + tid * 16,        ag + k0 + 32);
      gload16((char*)a_lds[cur ^ 1] + 4096 + tid * 16, ag + (size_t)64 * K + k0 + 32);
      gload16((char*)b_lds[cur ^ 1] + tid * 16,        bg + k0 + 32);
      gload16((char*)b_lds[cur ^ 1] + 4096 + tid * 16, bg + (size_t)64 * K + k0 + 32);
    }
    bf16x8 af[4], bf[4];
#pragma unroll
    for (int i = 0; i < 4; ++i) {
      af[i] = *(const bf16x8*)&a_lds[cur][wr * 64 + i * 16 + lr][lg * 8];
      bf[i] = *(const bf16x8*)&b_lds[cur][wc * 64 + i * 16 + lr][lg * 8];
    }
#pragma unroll
    for (int i = 0; i < 4; ++i)
#pragma unroll
      for (int j = 0; j < 4; ++j)
        acc[i][j] = MFMA16(af[i], bf[j], acc[i][j]);
    __syncthreads();
    cur ^= 1;
  }

  int matsel = fused ? (n0 >> 10) : 0;
  const float* bias = matsel == 0 ? b0 : matsel == 1 ? b1 : b2;
  float bs[4];
#pragma unroll
  for (int j = 0; j < 4; ++j) bs[j] = bias[(n0 + wc * 64 + j * 16 + lr) & 1023];

#pragma unroll
  for (int i = 0; i < 4; ++i) {
#pragma unroll
    for (int j = 0; j < 4; ++j) {
#pragma unroll
      for (int r = 0; r < 4; ++r) {
        int row = m0 + wr * 64 + i * 16 + lg * 4 + r;
        int col = n0 + wc * 64 + j * 16 + lr;
        float v = acc[i][j][r] + bs[j];
        if (!fused) {
          ((float*)o0)[(size_t)row * N + col] = v;
        } else {
          int nn = col & 1023;
          int bb = row >> 11, s = row & 2047, hh = nn >> 6, d = nn & 63;
          if (matsel == 2) {
            ((bf16_t*)o2)[((((size_t)bb * 16 + hh) * 64) + d) * 2048 + s] = (bf16_t)v;
          } else {
            bf16_t* o = matsel ? (bf16_t*)o1 : (bf16_t*)o0;
            if (matsel == 0) v *= 0.125f;   // fold 1/sqrt(hd) into q (exact)
            o[((((size_t)bb * 16 + hh) * 2048 + s) << 6) + d] = (bf16_t)v;
          }
        }
      }
    }
  }
}

// ---------------- fused attention ------------------------------------------
// flat grid 1024 (XCD-swizzled), 256 thr = 4 waves; wave owns 32 q-rows
// (2 subtiles of 16). K/V tiles (64 keys) double-buffered in LDS, XOR-swizzled
// via pre-swizzled global source. Swapped QK^T (mfma(K,Q)) -> lane holds
// 4 consecutive k per q-row -> packed b64 P writes, conflict-free P reads.
__global__ __launch_bounds__(256, 4) void attn_k(
    const bf16_t* __restrict__ q, const bf16_t* __restrict__ k,
    const bf16_t* __restrict__ vT, const float* __restrict__ mu_p,
    bf16_t* __restrict__ out)
{
  const int S = 2048;
  int hw = blockIdx.x;
  int vid = (hw & 7) * 128 + (hw >> 3);   // 16 blocks sharing (b,h) -> same XCD
  int qt = vid & 15;                      // q-tile of 128 rows
  int bh = vid >> 4;
  int h = bh & 15, b = bh >> 4;

  const bf16_t* qb = q  + ((size_t)bh * S + qt * 128) * 64;
  const bf16_t* kb = k  + (size_t)bh * S * 64;
  const bf16_t* vb = vT + (size_t)bh * 64 * S;
  const float emu = __expf(mu_p[0]);

  __shared__ __align__(16) bf16_t k_lds[2][64][64];   // [buf][k-local][hd], swz
  __shared__ __align__(16) bf16_t v_lds[2][64][64];   // [buf][hd][k-local], swz
  __shared__ __align__(16) bf16_t p_lds[4][16][64];   // per-wave [q][k], swz

  const int tid = threadIdx.x, l = tid & 63, w = tid >> 6;
  const int lr = l & 15, lg = l >> 4;
  const int swz = (lr & 7) << 4;

  // Q fragments in registers (loop-invariant): 2 subtiles x 2 k-chunks
  bf16x8 qa[2][2];
#pragma unroll
  for (int sub = 0; sub < 2; ++sub)
#pragma unroll
    for (int ch = 0; ch < 2; ++ch)
      qa[sub][ch] = *(const bf16x8*)(qb + (size_t)(w * 32 + sub * 16 + lr) * 64
                                     + ch * 32 + lg * 8);

  // staging geometry: lane tid writes LDS bytes tid*16 (+4096 for 2nd call);
  // source column pre-swizzled so swizzled reads see semantic layout.
  const int srow = tid >> 3;                       // 0..31
  const int ssw  = ((tid & 7) * 16) ^ ((srow & 7) << 4);

  f32x4 o[2][4] = {};
  float rsum[2] = {0.f, 0.f};

  {  // prologue: stage tile 0 into buf 0
#pragma unroll
    for (int c = 0; c < 2; ++c) {
      int row = srow + 32 * c;
      gload16((char*)k_lds[0] + c * 4096 + tid * 16,
              (const char*)kb + (size_t)row * 128 + ssw);
      gload16((char*)v_lds[0] + c * 4096 + tid * 16,
              (const char*)vb + (size_t)row * 4096 + ssw);
    }
  }
  __syncthreads();

  char* pbase = (char*)p_lds[w];
  int cur = 0;
  for (int t = 0; t < 32; ++t) {
    if (t + 1 < 32) {   // issue next-tile loads early; they drain at the barrier
      const char* ks = (const char*)kb + (size_t)(t + 1) * 64 * 128;
      const char* vs = (const char*)vb + (size_t)(t + 1) * 128;
#pragma unroll
      for (int c = 0; c < 2; ++c) {
        int row = srow + 32 * c;
        gload16((char*)k_lds[cur ^ 1] + c * 4096 + tid * 16, ks + (size_t)row * 128 + ssw);
        gload16((char*)v_lds[cur ^ 1] + c * 4096 + tid * 16, vs + (size_t)row * 4096 + ssw);
      }
    }

    bf16x8 kf[4][2];
#pragma unroll
    for (int cc = 0; cc < 4; ++cc)
#pragma unroll
      for (int ch = 0; ch < 2; ++ch)
        kf[cc][ch] = *(const bf16x8*)((const char*)k_lds[cur]
                       + (cc * 16 + lr) * 128 + ((ch * 64 + lg * 16) ^ swz));

#pragma unroll
    for (int sub = 0; sub < 2; ++sub) {
      // scores^T: mfma(K,Q): lane -> q=lr, k = cc*16 + 4*lg + r
      f32x4 sc4[4];
#pragma unroll
      for (int cc = 0; cc < 4; ++cc) {
        f32x4 a = {};
        a = MFMA16(kf[cc][0], qa[sub][0], a);
        a = MFMA16(kf[cc][1], qa[sub][1], a);
        sc4[cc] = a;
      }
      // w = e^2/(e+emu); packed b64 write of 4 consecutive k
#pragma unroll
      for (int cc = 0; cc < 4; ++cc) {
        bf16x4 pw;
#pragma unroll
        for (int r = 0; r < 4; ++r) {
          float e = __expf(sc4[cc][r]);
          float wgt = e * e * __builtin_amdgcn_rcpf(e + emu);
          rsum[sub] += wgt;
          pw[r] = (bf16_t)wgt;
        }
        *(bf16x4*)(pbase + lr * 128 + ((cc * 32 + lg * 8) ^ swz)) = pw;
      }
      // PV: O[16q x 64d] += P[16q x 64k] * V[64k x 64d]
      bf16x8 pa0 = *(const bf16x8*)(pbase + lr * 128 + ((lg * 16) ^ swz));
      bf16x8 pa1 = *(const bf16x8*)(pbase + lr * 128 + ((64 + lg * 16) ^ swz));
#pragma unroll
      for (int cc = 0; cc < 4; ++cc) {
        bf16x8 vf0 = *(const bf16x8*)((const char*)v_lds[cur]
                       + (cc * 16 + lr) * 128 + ((lg * 16) ^ swz));
        bf16x8 vf1 = *(const bf16x8*)((const char*)v_lds[cur]
                       + (cc * 16 + lr) * 128 + ((64 + lg * 16) ^ swz));
        o[sub][cc] = MFMA16(pa0, vf0, o[sub][cc]);
        o[sub][cc] = MFMA16(pa1, vf1, o[sub][cc]);
      }
    }
    __syncthreads();
    cur ^= 1;
  }

  // rowsum reduce (q = lr is lane-local; sum over lg groups), redistribute,
  // normalize, store.
#pragma unroll
  for (int sub = 0; sub < 2; ++sub) {
    float rs = rsum[sub];
    rs += __shfl_xor(rs, 16);
    rs += __shfl_xor(rs, 32);
    float rinv = __builtin_amdgcn_rcpf(rs);
    float ro[4];
#pragma unroll
    for (int r = 0; r < 4; ++r) {
      int src = (l & 48) | ((4 * lg + r) & 15);
      ro[r] = __shfl(rinv, src);
    }
#pragma unroll
    for (int cc = 0; cc < 4; ++cc)
#pragma unroll
      for (int r = 0; r < 4; ++r) {
        int srow_g = qt * 128 + w * 32 + sub * 16 + 4 * lg + r;
        int col = h * 64 + cc * 16 + lr;
        out[((size_t)b * 2048 + srow_g) * 1024 + col] = (bf16_t)(o[sub][cc][r] * ro[r]);
      }
  }
}

// ---------------------------------------------------------------------------
extern "C" void kernel_launch(void* const* d_in, const int* in_sizes, int n_in,
                              void* d_out, int out_size, void* d_ws, size_t ws_size,
                              hipStream_t stream) {
  const float* seq = (const float*)d_in[0];
  const float* g   = (const float*)d_in[1];
  const float* be  = (const float*)d_in[2];
  const float* Wq  = (const float*)d_in[3];
  const float* bq  = (const float*)d_in[4];
  const float* Wk  = (const float*)d_in[5];
  const float* bk  = (const float*)d_in[6];
  const float* Wv  = (const float*)d_in[7];
  const float* bv  = (const float*)d_in[8];
  const float* Wo  = (const float*)d_in[9];
  const float* bo  = (const float*)d_in[10];
  const float* mu  = (const float*)d_in[11];

  char* ws = (char*)d_ws;
  bf16_t* xb   = (bf16_t*)ws;  ws += (size_t)8192 * 1024 * 2;
  bf16_t* wAll = (bf16_t*)ws;  ws += (size_t)4 * 1024 * 1024 * 2;
  bf16_t* qb   = (bf16_t*)ws;  ws += (size_t)8192 * 1024 * 2;
  bf16_t* kbuf = (bf16_t*)ws;  ws += (size_t)8192 * 1024 * 2;
  bf16_t* vtb  = (bf16_t*)ws;  ws += (size_t)8192 * 1024 * 2;
  bf16_t* ab   = (bf16_t*)ws;  ws += (size_t)8192 * 1024 * 2;
  bf16_t* wqkv = wAll;                                  // [3072][1024] packed
  bf16_t* wob  = wAll + (size_t)3 * 1024 * 1024;

  dim3 blk(256);
  cvt_w_k<<<dim3(1024, 4), blk, 0, stream>>>(Wq, Wk, Wv, Wo, wAll);
  ln_k<<<dim3(8192), blk, 0, stream>>>(seq, g, be, xb);
  gemm_bt<<<dim3(24, 64), blk, 0, stream>>>(xb, wqkv, bq, bk, bv,
                                            qb, kbuf, vtb, 8192, 3072, 1024, 1);
  attn_k<<<dim3(1024), blk, 0, stream>>>(qb, kbuf, vtb, mu, ab);
  gemm_bt<<<dim3(8, 64), blk, 0, stream>>>(ab, wob, bo, nullptr, nullptr,
                                           d_out, nullptr, nullptr, 8192, 1024, 1024, 0);
}

// Round 3
// 282.519 us; speedup vs baseline: 1.2593x; 1.1783x over previous
//
#include <hip/hip_runtime.h>
#include <hip/hip_bf16.h>
#include <cstdint>
#include <cstddef>

// ---------------------------------------------------------------------------
// Attention block on MI355X (gfx950), bf16 MFMA everywhere.
//   x = LN(seq); q,k,v = x@W{q,k,v}.T + b (q pre-scaled by 0.125*log2e)
//   s' = q.k (in log2 domain); e = exp2(s'); w = e^2/(e+e^mu)
//   P = w / rowsum(w); out = (P @ v, heads merged) @ Wo.T + bo
// ---------------------------------------------------------------------------

typedef __bf16 bf16_t;
typedef __bf16 bf16x4 __attribute__((ext_vector_type(4)));
typedef __bf16 bf16x8 __attribute__((ext_vector_type(8)));
typedef float  f32x4  __attribute__((ext_vector_type(4)));

#define MFMA16(a, b, c) __builtin_amdgcn_mfma_f32_16x16x32_bf16((a), (b), (c), 0, 0, 0)

__device__ __forceinline__ void gload16(void* lds, const void* g) {
  __builtin_amdgcn_global_load_lds(
      (__attribute__((address_space(1))) void*)(uintptr_t)g,
      (__attribute__((address_space(3))) void*)(uint32_t)(uintptr_t)lds,
      16, 0, 0);
}

// ---------------- weights fp32 -> bf16 (4 x 1M elements, packed) -----------
__global__ __launch_bounds__(256) void cvt_w_k(
    const float* __restrict__ s0, const float* __restrict__ s1,
    const float* __restrict__ s2, const float* __restrict__ s3,
    bf16_t* __restrict__ dst)
{
  const float* src = blockIdx.y == 0 ? s0 : blockIdx.y == 1 ? s1
                   : blockIdx.y == 2 ? s2 : s3;
  int i = blockIdx.x * 256 + threadIdx.x;
  float4 v = ((const float4*)src)[i];
  bf16x4 o = { (bf16_t)v.x, (bf16_t)v.y, (bf16_t)v.z, (bf16_t)v.w };
  *(bf16x4*)(dst + (((size_t)blockIdx.y) << 20) + (size_t)i * 4) = o;
}

// ---------------- LayerNorm (row = 1024 fp32) -> bf16 ----------------------
__global__ __launch_bounds__(256) void ln_k(
    const float* __restrict__ x, const float* __restrict__ gamma,
    const float* __restrict__ beta, bf16_t* __restrict__ out)
{
  int row = blockIdx.x;
  int tid = threadIdx.x;
  float4 v = ((const float4*)(x + (size_t)row * 1024))[tid];
  float s  = v.x + v.y + v.z + v.w;
  float ss = v.x * v.x + v.y * v.y + v.z * v.z + v.w * v.w;
#pragma unroll
  for (int m = 1; m < 64; m <<= 1) { s += __shfl_xor(s, m); ss += __shfl_xor(ss, m); }
  __shared__ float sh_s[4], sh_q[4];
  int w = tid >> 6;
  if ((tid & 63) == 0) { sh_s[w] = s; sh_q[w] = ss; }
  __syncthreads();
  s  = sh_s[0] + sh_s[1] + sh_s[2] + sh_s[3];
  ss = sh_q[0] + sh_q[1] + sh_q[2] + sh_q[3];
  float mean = s * (1.0f / 1024.0f);
  float var  = ss * (1.0f / 1024.0f) - mean * mean;
  float rstd = rsqrtf(var + 1e-6f);
  float4 gv = ((const float4*)gamma)[tid];
  float4 bv = ((const float4*)beta)[tid];
  bf16x4 o = { (bf16_t)((v.x - mean) * rstd * gv.x + bv.x),
               (bf16_t)((v.y - mean) * rstd * gv.y + bv.y),
               (bf16_t)((v.z - mean) * rstd * gv.z + bv.z),
               (bf16_t)((v.w - mean) * rstd * gv.w + bv.w) };
  *(bf16x4*)(out + (size_t)row * 1024 + tid * 4) = o;
}

// ---------------- NT GEMM: C[M,N] = A[M,K] * Bw[N,K]^T + bias --------------
// 128x128 tile, BK=32, 2-phase double-buffered staging (one barrier/K-step).
// fused=1: N=3072 packed qkv -> scatter (q: [B,H,S,64] scaled 0.125*log2e,
//          k: same layout, v transposed [B,H,64,S]); fused=0: fp32 out.
__global__ __launch_bounds__(256) void gemm_bt(
    const bf16_t* __restrict__ A, const bf16_t* __restrict__ Bw,
    const float* __restrict__ b0, const float* __restrict__ b1,
    const float* __restrict__ b2,
    void* __restrict__ o0, void* __restrict__ o1, void* __restrict__ o2,
    int M, int N, int K, int fused)
{
  __shared__ __align__(16) bf16_t a_lds[2][128][32];
  __shared__ __align__(16) bf16_t b_lds[2][128][32];
  const int tid = threadIdx.x;
  const int l = tid & 63, w = tid >> 6;
  const int wr = w >> 1, wc = w & 1;
  const int m0 = blockIdx.y * 128, n0 = blockIdx.x * 128;
  const int lr = l & 15, lg = l >> 4;

  f32x4 acc[4][4] = {};

  const int srow = tid >> 2;
  const int scol = (tid & 3) * 8;
  const bf16_t* ag = A  + (size_t)(m0 + srow) * K + scol;
  const bf16_t* bg = Bw + (size_t)(n0 + srow) * K + scol;

  gload16((char*)a_lds[0] + tid * 16,        ag);
  gload16((char*)a_lds[0] + 4096 + tid * 16, ag + (size_t)64 * K);
  gload16((char*)b_lds[0] + tid * 16,        bg);
  gload16((char*)b_lds[0] + 4096 + tid * 16, bg + (size_t)64 * K);
  __syncthreads();

  int cur = 0;
  for (int k0 = 0; k0 < K; k0 += 32) {
    if (k0 + 32 < K) {
      gload16((char*)a_lds[cur ^ 1] + tid * 16,        ag + k0 + 32);
      gload16((char*)a_lds[cur ^ 1] + 4096 + tid * 16, ag + (size_t)64 * K + k0 + 32);
      gload16((char*)b_lds[cur ^ 1] + tid * 16,        bg + k0 + 32);
      gload16((char*)b_lds[cur ^ 1] + 4096 + tid * 16, bg + (size_t)64 * K + k0 + 32);
    }
    bf16x8 af[4], bf[4];
#pragma unroll
    for (int i = 0; i < 4; ++i) {
      af[i] = *(const bf16x8*)&a_lds[cur][wr * 64 + i * 16 + lr][lg * 8];
      bf[i] = *(const bf16x8*)&b_lds[cur][wc * 64 + i * 16 + lr][lg * 8];
    }
#pragma unroll
    for (int i = 0; i < 4; ++i)
#pragma unroll
      for (int j = 0; j < 4; ++j)
        acc[i][j] = MFMA16(af[i], bf[j], acc[i][j]);
    __syncthreads();
    cur ^= 1;
  }

  int matsel = fused ? (n0 >> 10) : 0;
  const float* bias = matsel == 0 ? b0 : matsel == 1 ? b1 : b2;
  float bs[4];
#pragma unroll
  for (int j = 0; j < 4; ++j) bs[j] = bias[(n0 + wc * 64 + j * 16 + lr) & 1023];

#pragma unroll
  for (int i = 0; i < 4; ++i) {
#pragma unroll
    for (int j = 0; j < 4; ++j) {
#pragma unroll
      for (int r = 0; r < 4; ++r) {
        int row = m0 + wr * 64 + i * 16 + lg * 4 + r;
        int col = n0 + wc * 64 + j * 16 + lr;
        float v = acc[i][j][r] + bs[j];
        if (!fused) {
          ((float*)o0)[(size_t)row * N + col] = v;
        } else {
          int nn = col & 1023;
          int bb = row >> 11, s = row & 2047, hh = nn >> 6, d = nn & 63;
          if (matsel == 2) {
            ((bf16_t*)o2)[((((size_t)bb * 16 + hh) * 64) + d) * 2048 + s] = (bf16_t)v;
          } else {
            bf16_t* o = matsel ? (bf16_t*)o1 : (bf16_t*)o0;
            // fold 1/sqrt(hd) * log2(e) into q -> scores arrive in log2 domain
            if (matsel == 0) v *= 0.18033688011112042f;
            o[((((size_t)bb * 16 + hh) * 2048 + s) << 6) + d] = (bf16_t)v;
          }
        }
      }
    }
  }
}

// ---------------- fused attention ------------------------------------------
// flat grid 1024 (XCD-swizzled), 256 thr = 4 waves; wave owns 32 q-rows.
// K/V tiles (64 keys) double-buffered in LDS, XOR-swizzled via pre-swizzled
// global source. Swapped QK^T (mfma(K,Q)) -> packed b64 P writes.
// NOTE: no min-waves launch bound — round-2's (256,4) capped VGPR at ~128
// and spilled ~300 MB/dispatch to scratch.
__global__ __launch_bounds__(256) void attn_k(
    const bf16_t* __restrict__ q, const bf16_t* __restrict__ k,
    const bf16_t* __restrict__ vT, const float* __restrict__ mu_p,
    bf16_t* __restrict__ out)
{
  const int S = 2048;
  int hw = blockIdx.x;
  int vid = (hw & 7) * 128 + (hw >> 3);   // 16 blocks sharing (b,h) -> same XCD
  int qt = vid & 15;
  int bh = vid >> 4;
  int h = bh & 15, b = bh >> 4;

  const bf16_t* qb = q  + ((size_t)bh * S + qt * 128) * 64;
  const bf16_t* kb = k  + (size_t)bh * S * 64;
  const bf16_t* vb = vT + (size_t)bh * 64 * S;
  const float emu = __expf(mu_p[0]);      // e^mu (natural)

  __shared__ __align__(16) bf16_t k_lds[2][64][64];
  __shared__ __align__(16) bf16_t v_lds[2][64][64];
  __shared__ __align__(16) bf16_t p_lds[4][16][64];

  const int tid = threadIdx.x, l = tid & 63, w = tid >> 6;
  const int lr = l & 15, lg = l >> 4;
  const int swz = (lr & 7) << 4;

  bf16x8 qa[2][2];
#pragma unroll
  for (int sub = 0; sub < 2; ++sub)
#pragma unroll
    for (int ch = 0; ch < 2; ++ch)
      qa[sub][ch] = *(const bf16x8*)(qb + (size_t)(w * 32 + sub * 16 + lr) * 64
                                     + ch * 32 + lg * 8);

  const int srow = tid >> 3;
  const int ssw  = ((tid & 7) * 16) ^ ((srow & 7) << 4);

  f32x4 o[2][4] = {};
  float rsum[2] = {0.f, 0.f};

#pragma unroll
  for (int c = 0; c < 2; ++c) {
    int row = srow + 32 * c;
    gload16((char*)k_lds[0] + c * 4096 + tid * 16,
            (const char*)kb + (size_t)row * 128 + ssw);
    gload16((char*)v_lds[0] + c * 4096 + tid * 16,
            (const char*)vb + (size_t)row * 4096 + ssw);
  }
  __syncthreads();

  char* pbase = (char*)p_lds[w];
  int cur = 0;
  for (int t = 0; t < 32; ++t) {
    if (t + 1 < 32) {
      const char* ks = (const char*)kb + (size_t)(t + 1) * 64 * 128;
      const char* vs = (const char*)vb + (size_t)(t + 1) * 128;
#pragma unroll
      for (int c = 0; c < 2; ++c) {
        int row = srow + 32 * c;
        gload16((char*)k_lds[cur ^ 1] + c * 4096 + tid * 16, ks + (size_t)row * 128 + ssw);
        gload16((char*)v_lds[cur ^ 1] + c * 4096 + tid * 16, vs + (size_t)row * 4096 + ssw);
      }
    }

    bf16x8 kf[4][2];
#pragma unroll
    for (int cc = 0; cc < 4; ++cc)
#pragma unroll
      for (int ch = 0; ch < 2; ++ch)
        kf[cc][ch] = *(const bf16x8*)((const char*)k_lds[cur]
                       + (cc * 16 + lr) * 128 + ((ch * 64 + lg * 16) ^ swz));

#pragma unroll
    for (int sub = 0; sub < 2; ++sub) {
      f32x4 sc4[4];
#pragma unroll
      for (int cc = 0; cc < 4; ++cc) {
        f32x4 a = {};
        a = MFMA16(kf[cc][0], qa[sub][0], a);
        a = MFMA16(kf[cc][1], qa[sub][1], a);
        sc4[cc] = a;
      }
#pragma unroll
      for (int cc = 0; cc < 4; ++cc) {
        bf16x4 pw;
#pragma unroll
        for (int r = 0; r < 4; ++r) {
          float e = exp2f(sc4[cc][r]);     // scores already in log2 domain
          float wgt = e * e * __builtin_amdgcn_rcpf(e + emu);
          rsum[sub] += wgt;
          pw[r] = (bf16_t)wgt;
        }
        *(bf16x4*)(pbase + lr * 128 + ((cc * 32 + lg * 8) ^ swz)) = pw;
      }
      bf16x8 pa0 = *(const bf16x8*)(pbase + lr * 128 + ((lg * 16) ^ swz));
      bf16x8 pa1 = *(const bf16x8*)(pbase + lr * 128 + ((64 + lg * 16) ^ swz));
#pragma unroll
      for (int cc = 0; cc < 4; ++cc) {
        bf16x8 vf0 = *(const bf16x8*)((const char*)v_lds[cur]
                       + (cc * 16 + lr) * 128 + ((lg * 16) ^ swz));
        bf16x8 vf1 = *(const bf16x8*)((const char*)v_lds[cur]
                       + (cc * 16 + lr) * 128 + ((64 + lg * 16) ^ swz));
        o[sub][cc] = MFMA16(pa0, vf0, o[sub][cc]);
        o[sub][cc] = MFMA16(pa1, vf1, o[sub][cc]);
      }
    }
    __syncthreads();
    cur ^= 1;
  }

#pragma unroll
  for (int sub = 0; sub < 2; ++sub) {
    float rs = rsum[sub];
    rs += __shfl_xor(rs, 16);
    rs += __shfl_xor(rs, 32);
    float rinv = __builtin_amdgcn_rcpf(rs);
    float ro[4];
#pragma unroll
    for (int r = 0; r < 4; ++r) {
      int src = (l & 48) | ((4 * lg + r) & 15);
      ro[r] = __shfl(rinv, src);
    }
#pragma unroll
    for (int cc = 0; cc < 4; ++cc)
#pragma unroll
      for (int r = 0; r < 4; ++r) {
        int srow_g = qt * 128 + w * 32 + sub * 16 + 4 * lg + r;
        int col = h * 64 + cc * 16 + lr;
        out[((size_t)b * 2048 + srow_g) * 1024 + col] = (bf16_t)(o[sub][cc][r] * ro[r]);
      }
  }
}

// ---------------------------------------------------------------------------
extern "C" void kernel_launch(void* const* d_in, const int* in_sizes, int n_in,
                              void* d_out, int out_size, void* d_ws, size_t ws_size,
                              hipStream_t stream) {
  const float* seq = (const float*)d_in[0];
  const float* g   = (const float*)d_in[1];
  const float* be  = (const float*)d_in[2];
  const float* Wq  = (const float*)d_in[3];
  const float* bq  = (const float*)d_in[4];
  const float* Wk  = (const float*)d_in[5];
  const float* bk  = (const float*)d_in[6];
  const float* Wv  = (const float*)d_in[7];
  const float* bv  = (const float*)d_in[8];
  const float* Wo  = (const float*)d_in[9];
  const float* bo  = (const float*)d_in[10];
  const float* mu  = (const float*)d_in[11];

  char* ws = (char*)d_ws;
  bf16_t* xb   = (bf16_t*)ws;  ws += (size_t)8192 * 1024 * 2;
  bf16_t* wAll = (bf16_t*)ws;  ws += (size_t)4 * 1024 * 1024 * 2;
  bf16_t* qb   = (bf16_t*)ws;  ws += (size_t)8192 * 1024 * 2;
  bf16_t* kbuf = (bf16_t*)ws;  ws += (size_t)8192 * 1024 * 2;
  bf16_t* vtb  = (bf16_t*)ws;  ws += (size_t)8192 * 1024 * 2;
  bf16_t* ab   = (bf16_t*)ws;  ws += (size_t)8192 * 1024 * 2;
  bf16_t* wqkv = wAll;
  bf16_t* wob  = wAll + (size_t)3 * 1024 * 1024;

  dim3 blk(256);
  cvt_w_k<<<dim3(1024, 4), blk, 0, stream>>>(Wq, Wk, Wv, Wo, wAll);
  ln_k<<<dim3(8192), blk, 0, stream>>>(seq, g, be, xb);
  gemm_bt<<<dim3(24, 64), blk, 0, stream>>>(xb, wqkv, bq, bk, bv,
                                            qb, kbuf, vtb, 8192, 3072, 1024, 1);
  attn_k<<<dim3(1024), blk, 0, stream>>>(qb, kbuf, vtb, mu, ab);
  gemm_bt<<<dim3(8, 64), blk, 0, stream>>>(ab, wob, bo, nullptr, nullptr,
                                           d_out, nullptr, nullptr, 8192, 1024, 1024, 0);
}

// Round 4
// 242.250 us; speedup vs baseline: 1.4686x; 1.1662x over previous
//
#include <hip/hip_runtime.h>
#include <hip/hip_bf16.h>
#include <cstdint>
#include <cstddef>

// ---------------------------------------------------------------------------
// Attention block on MI355X (gfx950), bf16 MFMA everywhere.
//   x = LN(seq); q,k,v = x@W{q,k,v}.T + b (q pre-scaled by 0.125*log2e)
//   s' = q.k (log2 domain); e = 2^s' = exp(s_nat); w = e^2/(e+e^mu)
//   P = w / rowsum(w); out = (P @ v, heads merged) @ Wo.T + bo
// ---------------------------------------------------------------------------

typedef __bf16 bf16_t;
typedef __bf16 bf16x4 __attribute__((ext_vector_type(4)));
typedef __bf16 bf16x8 __attribute__((ext_vector_type(8)));
typedef float  f32x4  __attribute__((ext_vector_type(4)));

#define MFMA16(a, b, c) __builtin_amdgcn_mfma_f32_16x16x32_bf16((a), (b), (c), 0, 0, 0)

// raw v_exp_f32 (libm exp2f is NOT the fast path without -ffast-math)
#if __has_builtin(__builtin_amdgcn_exp2f)
#define VEXP2(x) __builtin_amdgcn_exp2f(x)
#else
#define VEXP2(x) __expf((x) * 0.6931471805599453f)
#endif

__device__ __forceinline__ void gload16(void* lds, const void* g) {
  __builtin_amdgcn_global_load_lds(
      (__attribute__((address_space(1))) void*)(uintptr_t)g,
      (__attribute__((address_space(3))) void*)(uint32_t)(uintptr_t)lds,
      16, 0, 0);
}

// ---------------- weights fp32 -> bf16 (4 x 1M elements, packed) -----------
__global__ __launch_bounds__(256) void cvt_w_k(
    const float* __restrict__ s0, const float* __restrict__ s1,
    const float* __restrict__ s2, const float* __restrict__ s3,
    bf16_t* __restrict__ dst)
{
  const float* src = blockIdx.y == 0 ? s0 : blockIdx.y == 1 ? s1
                   : blockIdx.y == 2 ? s2 : s3;
  int i = blockIdx.x * 256 + threadIdx.x;
  float4 v = ((const float4*)src)[i];
  bf16x4 o = { (bf16_t)v.x, (bf16_t)v.y, (bf16_t)v.z, (bf16_t)v.w };
  *(bf16x4*)(dst + (((size_t)blockIdx.y) << 20) + (size_t)i * 4) = o;
}

// ---------------- LayerNorm (row = 1024 fp32) -> bf16 ----------------------
__global__ __launch_bounds__(256) void ln_k(
    const float* __restrict__ x, const float* __restrict__ gamma,
    const float* __restrict__ beta, bf16_t* __restrict__ out)
{
  int row = blockIdx.x;
  int tid = threadIdx.x;
  float4 v = ((const float4*)(x + (size_t)row * 1024))[tid];
  float s  = v.x + v.y + v.z + v.w;
  float ss = v.x * v.x + v.y * v.y + v.z * v.z + v.w * v.w;
#pragma unroll
  for (int m = 1; m < 64; m <<= 1) { s += __shfl_xor(s, m); ss += __shfl_xor(ss, m); }
  __shared__ float sh_s[4], sh_q[4];
  int w = tid >> 6;
  if ((tid & 63) == 0) { sh_s[w] = s; sh_q[w] = ss; }
  __syncthreads();
  s  = sh_s[0] + sh_s[1] + sh_s[2] + sh_s[3];
  ss = sh_q[0] + sh_q[1] + sh_q[2] + sh_q[3];
  float mean = s * (1.0f / 1024.0f);
  float var  = ss * (1.0f / 1024.0f) - mean * mean;
  float rstd = rsqrtf(var + 1e-6f);
  float4 gv = ((const float4*)gamma)[tid];
  float4 bv = ((const float4*)beta)[tid];
  bf16x4 o = { (bf16_t)((v.x - mean) * rstd * gv.x + bv.x),
               (bf16_t)((v.y - mean) * rstd * gv.y + bv.y),
               (bf16_t)((v.z - mean) * rstd * gv.z + bv.z),
               (bf16_t)((v.w - mean) * rstd * gv.w + bv.w) };
  *(bf16x4*)(out + (size_t)row * 1024 + tid * 4) = o;
}

// ---------------- NT GEMM: C[M,N] = A[M,K] * Bw[N,K]^T + bias --------------
__global__ __launch_bounds__(256) void gemm_bt(
    const bf16_t* __restrict__ A, const bf16_t* __restrict__ Bw,
    const float* __restrict__ b0, const float* __restrict__ b1,
    const float* __restrict__ b2,
    void* __restrict__ o0, void* __restrict__ o1, void* __restrict__ o2,
    int M, int N, int K, int fused)
{
  __shared__ __align__(16) bf16_t a_lds[2][128][32];
  __shared__ __align__(16) bf16_t b_lds[2][128][32];
  const int tid = threadIdx.x;
  const int l = tid & 63, w = tid >> 6;
  const int wr = w >> 1, wc = w & 1;
  const int m0 = blockIdx.y * 128, n0 = blockIdx.x * 128;
  const int lr = l & 15, lg = l >> 4;

  f32x4 acc[4][4] = {};

  const int srow = tid >> 2;
  const int scol = (tid & 3) * 8;
  const bf16_t* ag = A  + (size_t)(m0 + srow) * K + scol;
  const bf16_t* bg = Bw + (size_t)(n0 + srow) * K + scol;

  gload16((char*)a_lds[0] + tid * 16,        ag);
  gload16((char*)a_lds[0] + 4096 + tid * 16, ag + (size_t)64 * K);
  gload16((char*)b_lds[0] + tid * 16,        bg);
  gload16((char*)b_lds[0] + 4096 + tid * 16, bg + (size_t)64 * K);
  __syncthreads();

  int cur = 0;
  for (int k0 = 0; k0 < K; k0 += 32) {
    if (k0 + 32 < K) {
      gload16((char*)a_lds[cur ^ 1] + tid * 16,        ag + k0 + 32);
      gload16((char*)a_lds[cur ^ 1] + 4096 + tid * 16, ag + (size_t)64 * K + k0 + 32);
      gload16((char*)b_lds[cur ^ 1] + tid * 16,        bg + k0 + 32);
      gload16((char*)b_lds[cur ^ 1] + 4096 + tid * 16, bg + (size_t)64 * K + k0 + 32);
    }
    bf16x8 af[4], bf[4];
#pragma unroll
    for (int i = 0; i < 4; ++i) {
      af[i] = *(const bf16x8*)&a_lds[cur][wr * 64 + i * 16 + lr][lg * 8];
      bf[i] = *(const bf16x8*)&b_lds[cur][wc * 64 + i * 16 + lr][lg * 8];
    }
#pragma unroll
    for (int i = 0; i < 4; ++i)
#pragma unroll
      for (int j = 0; j < 4; ++j)
        acc[i][j] = MFMA16(af[i], bf[j], acc[i][j]);
    __syncthreads();
    cur ^= 1;
  }

  int matsel = fused ? (n0 >> 10) : 0;
  const float* bias = matsel == 0 ? b0 : matsel == 1 ? b1 : b2;
  float bs[4];
#pragma unroll
  for (int j = 0; j < 4; ++j) bs[j] = bias[(n0 + wc * 64 + j * 16 + lr) & 1023];

#pragma unroll
  for (int i = 0; i < 4; ++i) {
#pragma unroll
    for (int j = 0; j < 4; ++j) {
#pragma unroll
      for (int r = 0; r < 4; ++r) {
        int row = m0 + wr * 64 + i * 16 + lg * 4 + r;
        int col = n0 + wc * 64 + j * 16 + lr;
        float v = acc[i][j][r] + bs[j];
        if (!fused) {
          ((float*)o0)[(size_t)row * N + col] = v;
        } else {
          int nn = col & 1023;
          int bb = row >> 11, s = row & 2047, hh = nn >> 6, d = nn & 63;
          if (matsel == 2) {
            ((bf16_t*)o2)[((((size_t)bb * 16 + hh) * 64) + d) * 2048 + s] = (bf16_t)v;
          } else {
            bf16_t* o = matsel ? (bf16_t*)o1 : (bf16_t*)o0;
            // fold 1/sqrt(hd) * log2(e) into q -> scores arrive in log2 domain
            if (matsel == 0) v *= 0.18033688011112042f;
            o[((((size_t)bb * 16 + hh) * 2048 + s) << 6) + d] = (bf16_t)v;
          }
        }
      }
    }
  }
}

// ---------------- fused attention ------------------------------------------
// flat grid 1024 (XCD-swizzled), 256 thr = 4 waves; wave owns 32 q-rows.
// K/V 64-key tiles double-buffered in LDS (XOR-swizzled via pre-swizzled
// global source). Swapped QK^T (mfma(K,Q)) -> packed b64 P writes.
// t-loop unrolled x2 so `cur` constant-folds -> LDS addrs loop-invariant.
__global__ __launch_bounds__(256) void attn_k(
    const bf16_t* __restrict__ q, const bf16_t* __restrict__ k,
    const bf16_t* __restrict__ vT, const float* __restrict__ mu_p,
    bf16_t* __restrict__ out)
{
  const int S = 2048;
  int hw = blockIdx.x;
  int vid = (hw & 7) * 128 + (hw >> 3);
  int qt = vid & 15;
  int bh = vid >> 4;
  int h = bh & 15, b = bh >> 4;

  const bf16_t* qb = q  + ((size_t)bh * S + qt * 128) * 64;
  const char* kbase = (const char*)(k  + (size_t)bh * S * 64);
  const char* vbase = (const char*)(vT + (size_t)bh * 64 * S);
  const float emu = __expf(mu_p[0]);      // e^mu (natural)

  __shared__ __align__(16) bf16_t k_lds[2][64][64];
  __shared__ __align__(16) bf16_t v_lds[2][64][64];
  __shared__ __align__(16) bf16_t p_lds[4][16][64];

  const int tid = threadIdx.x, l = tid & 63, w = tid >> 6;
  const int lr = l & 15, lg = l >> 4;
  const int swz = (lr & 7) << 4;

  bf16x8 qa[2][2];
#pragma unroll
  for (int sub = 0; sub < 2; ++sub)
#pragma unroll
    for (int ch = 0; ch < 2; ++ch)
      qa[sub][ch] = *(const bf16x8*)(qb + (size_t)(w * 32 + sub * 16 + lr) * 64
                                     + ch * 32 + lg * 8);

  // 32-bit staging offsets from uniform bases (saddr-friendly)
  const int srow = tid >> 3;
  const int ssw  = ((tid & 7) * 16) ^ ((srow & 7) << 4);
  const int koff = srow * 128 + ssw;       // +c*4096, +t*8192
  const int voff = srow * 4096 + ssw;      // +c*131072, +t*128

  f32x4 o[2][4] = {};
  f32x4 rsum4[2] = {};

#pragma unroll
  for (int c = 0; c < 2; ++c) {
    gload16((char*)k_lds[0] + c * 4096 + tid * 16, kbase + koff + c * 4096);
    gload16((char*)v_lds[0] + c * 4096 + tid * 16, vbase + voff + c * 131072);
  }
  __syncthreads();

  char* pbase = (char*)p_lds[w];
#pragma unroll 2
  for (int t = 0; t < 32; ++t) {
    const int cur = t & 1;                 // constant after unroll-by-2
    if (t + 1 < 32) {
#pragma unroll
      for (int c = 0; c < 2; ++c) {
        gload16((char*)k_lds[cur ^ 1] + c * 4096 + tid * 16,
                kbase + koff + c * 4096 + (t + 1) * 8192);
        gload16((char*)v_lds[cur ^ 1] + c * 4096 + tid * 16,
                vbase + voff + c * 131072 + (t + 1) * 128);
      }
    }

    bf16x8 kf[4][2];
#pragma unroll
    for (int cc = 0; cc < 4; ++cc)
#pragma unroll
      for (int ch = 0; ch < 2; ++ch)
        kf[cc][ch] = *(const bf16x8*)((const char*)k_lds[cur]
                       + (cc * 16 + lr) * 128 + ((ch * 64 + lg * 16) ^ swz));

#pragma unroll
    for (int sub = 0; sub < 2; ++sub) {
      f32x4 sc4[4];
#pragma unroll
      for (int cc = 0; cc < 4; ++cc) {
        f32x4 a = {};
        a = MFMA16(kf[cc][0], qa[sub][0], a);
        a = MFMA16(kf[cc][1], qa[sub][1], a);
        sc4[cc] = a;
      }
#pragma unroll
      for (int cc = 0; cc < 4; ++cc) {
        bf16x4 pw;
        f32x4 wv;
#pragma unroll
        for (int r = 0; r < 4; ++r) {
          float e = VEXP2(sc4[cc][r]);     // scores already in log2 domain
          float wgt = e * e * __builtin_amdgcn_rcpf(e + emu);
          wv[r] = wgt;
          pw[r] = (bf16_t)wgt;
        }
        rsum4[sub] += wv;
        *(bf16x4*)(pbase + lr * 128 + ((cc * 32 + lg * 8) ^ swz)) = pw;
      }
      bf16x8 pa0 = *(const bf16x8*)(pbase + lr * 128 + ((lg * 16) ^ swz));
      bf16x8 pa1 = *(const bf16x8*)(pbase + lr * 128 + ((64 + lg * 16) ^ swz));
#pragma unroll
      for (int cc = 0; cc < 4; ++cc) {
        bf16x8 vf0 = *(const bf16x8*)((const char*)v_lds[cur]
                       + (cc * 16 + lr) * 128 + ((lg * 16) ^ swz));
        bf16x8 vf1 = *(const bf16x8*)((const char*)v_lds[cur]
                       + (cc * 16 + lr) * 128 + ((64 + lg * 16) ^ swz));
        o[sub][cc] = MFMA16(pa0, vf0, o[sub][cc]);
        o[sub][cc] = MFMA16(pa1, vf1, o[sub][cc]);
      }
    }
    __syncthreads();
  }

#pragma unroll
  for (int sub = 0; sub < 2; ++sub) {
    float rs = (rsum4[sub][0] + rsum4[sub][1]) + (rsum4[sub][2] + rsum4[sub][3]);
    rs += __shfl_xor(rs, 16);
    rs += __shfl_xor(rs, 32);
    float rinv = __builtin_amdgcn_rcpf(rs);
    float ro[4];
#pragma unroll
    for (int r = 0; r < 4; ++r) {
      int src = (l & 48) | ((4 * lg + r) & 15);
      ro[r] = __shfl(rinv, src);
    }
#pragma unroll
    for (int cc = 0; cc < 4; ++cc)
#pragma unroll
      for (int r = 0; r < 4; ++r) {
        int srow_g = qt * 128 + w * 32 + sub * 16 + 4 * lg + r;
        int col = h * 64 + cc * 16 + lr;
        out[((size_t)b * 2048 + srow_g) * 1024 + col] = (bf16_t)(o[sub][cc][r] * ro[r]);
      }
  }
}

// ---------------------------------------------------------------------------
extern "C" void kernel_launch(void* const* d_in, const int* in_sizes, int n_in,
                              void* d_out, int out_size, void* d_ws, size_t ws_size,
                              hipStream_t stream) {
  const float* seq = (const float*)d_in[0];
  const float* g   = (const float*)d_in[1];
  const float* be  = (const float*)d_in[2];
  const float* Wq  = (const float*)d_in[3];
  const float* bq  = (const float*)d_in[4];
  const float* Wk  = (const float*)d_in[5];
  const float* bk  = (const float*)d_in[6];
  const float* Wv  = (const float*)d_in[7];
  const float* bv  = (const float*)d_in[8];
  const float* Wo  = (const float*)d_in[9];
  const float* bo  = (const float*)d_in[10];
  const float* mu  = (const float*)d_in[11];

  char* ws = (char*)d_ws;
  bf16_t* xb   = (bf16_t*)ws;  ws += (size_t)8192 * 1024 * 2;
  bf16_t* wAll = (bf16_t*)ws;  ws += (size_t)4 * 1024 * 1024 * 2;
  bf16_t* qb   = (bf16_t*)ws;  ws += (size_t)8192 * 1024 * 2;
  bf16_t* kbuf = (bf16_t*)ws;  ws += (size_t)8192 * 1024 * 2;
  bf16_t* vtb  = (bf16_t*)ws;  ws += (size_t)8192 * 1024 * 2;
  bf16_t* ab   = (bf16_t*)ws;  ws += (size_t)8192 * 1024 * 2;
  bf16_t* wqkv = wAll;
  bf16_t* wob  = wAll + (size_t)3 * 1024 * 1024;

  dim3 blk(256);
  cvt_w_k<<<dim3(1024, 4), blk, 0, stream>>>(Wq, Wk, Wv, Wo, wAll);
  ln_k<<<dim3(8192), blk, 0, stream>>>(seq, g, be, xb);
  gemm_bt<<<dim3(24, 64), blk, 0, stream>>>(xb, wqkv, bq, bk, bv,
                                            qb, kbuf, vtb, 8192, 3072, 1024, 1);
  attn_k<<<dim3(1024), blk, 0, stream>>>(qb, kbuf, vtb, mu, ab);
  gemm_bt<<<dim3(8, 64), blk, 0, stream>>>(ab, wob, bo, nullptr, nullptr,
                                           d_out, nullptr, nullptr, 8192, 1024, 1024, 0);
}